// Round 8
// baseline (200.448 us; speedup 1.0000x reference)
//
#include <hip/hip_runtime.h>

typedef _Float16 half8 __attribute__((ext_vector_type(8)));
typedef float f16v __attribute__((ext_vector_type(16)));
typedef float f4 __attribute__((ext_vector_type(4)));
typedef unsigned long long ull;

#define X_SLAB   1048576            // 32^4
#define PLANE_BYTES (34*36*4*2)     // 9792: one (j1,j2) plane [j3<34][j4<36][t<4] f16
#define RPT_SITES (34*34*34*36)     // 1,414,944 sites (8B each)
#define RPT_OFF  65536              // byte offset of rp_t in ws (tab before it)
#define RPT_SLACK 4096
#define TAB_N    (3*6*3*512)        // 27648 f16 entries
#define TAB_ELEMS  (4*81*8)         // fp32 fallback table

// ---------------------------------------------------------------------------
// prep: identical to R7 (kept byte-identical for clean subtraction).
// ---------------------------------------------------------------------------
__global__ __launch_bounds__(256)
void prep(const float* __restrict__ x, const float* __restrict__ w,
          ull* __restrict__ rpt, _Float16* __restrict__ tabm) {
    unsigned s = blockIdx.x * 256 + threadIdx.x;
    if (s < RPT_SITES) {
        unsigned q = s;
        int j4 = q % 36; q /= 36;
        int j3 = q % 34; q /= 34;
        int j2 = q % 34; q /= 34;
        int j1 = q;
        union { _Float16 h[4]; ull u; } pk;
        pk.u = 0ull;
        if (j1 >= 1 && j1 <= 32 && j2 >= 1 && j2 <= 32 &&
            j3 >= 1 && j3 <= 32 && j4 >= 1 && j4 <= 32) {
            size_t off = (size_t)(j1-1)*32768 + (j2-1)*1024 + (j3-1)*32 + (j4-1);
            #pragma unroll
            for (int t = 0; t < 4; ++t)
                pk.h[t] = (_Float16)fmaxf(x[(size_t)t*X_SLAB + off], 0.f);
        }
        rpt[s] = pk.u;
    }
    if (blockIdx.x == 0) {
        for (int idx = threadIdx.x; idx < TAB_N; idx += 256) {
            int j = idx & 7, l = (idx >> 3) & 63, slice = idx >> 9;   // slice<54
            int p4 = slice % 3, j2rel = (slice/3) % 6, p2 = slice/18;
            int n32 = l & 31;
            int d2 = n32 >> 3, n8 = n32 & 7;
            int k = 8*(l>>5) + j;
            int p5h = k >> 2, t = k & 3;
            int p3 = j2rel - d2;
            float val = 0.f;
            if (p5h < 3 && p3 >= 0 && p3 <= 2) {
                int br = n8 & 1, sc = n8 >> 1, s1 = sc >> 1, s2 = sc & 1;
                int t1 = t >> 1, t2 = t & 1;
                int a = t1 - s1 + 1, b = t2 - s2 + 1;
                int widx = (br == 0)
                    ? (a*243 + b*81 + p2*27 + p3*9 + p4*3 + p5h)
                    : (b*243 + a*81 + p4*27 + p5h*9 + p2*3 + p3);
                val = w[widx];
            }
            tabm[idx] = (_Float16)val;
        }
    }
}

// ---------------------------------------------------------------------------
// conv_mfma: byte-identical to R7. Launched 5x this round (idempotent) to
// measure its true marginal duration: conv = (T_r8 - T_r7) / 4.
// ---------------------------------------------------------------------------
__global__ __launch_bounds__(256)
void conv_mfma(const float* __restrict__ x, const ull* __restrict__ rpt,
               const _Float16* __restrict__ tabm, float* __restrict__ out) {
    __shared__ unsigned char msk[2048];

    const int tid  = threadIdx.x;
    const int lane = tid & 63;
    const int wv   = tid >> 6;                     // 0..3
    const int e2b  = blockIdx.x * 4;
    const int e1   = blockIdx.y;
    const int bz   = blockIdx.z;                   // e3 half
    const size_t pbase = (size_t)e1*32768 + (size_t)e2b*1024 + (size_t)bz*512;

    {
        int p0 = tid * 8;                          // 0..2040, no d2 crossing
        int d2 = p0 >> 9, rem = p0 & 511;
        const float* xb = x + pbase + (size_t)d2*1024 + rem;
        #pragma unroll
        for (int g = 0; g < 2; ++g) {
            f4 a0 = *(const f4*)(xb + (size_t)0*X_SLAB + 4*g);
            f4 a1 = *(const f4*)(xb + (size_t)1*X_SLAB + 4*g);
            f4 a2 = *(const f4*)(xb + (size_t)2*X_SLAB + 4*g);
            f4 a3 = *(const f4*)(xb + (size_t)3*X_SLAB + 4*g);
            unsigned wbits = 0;
            #pragma unroll
            for (int q = 0; q < 4; ++q) {
                unsigned b = (a0[q] != 0.f ? 1u : 0u) | (a1[q] != 0.f ? 2u : 0u)
                           | (a2[q] != 0.f ? 4u : 0u) | (a3[q] != 0.f ? 8u : 0u);
                wbits |= b << (8*q);
            }
            *(unsigned*)&msk[p0 + 4*g] = wbits;
        }
    }
    __syncthreads();

    f16v acc[4];
    #pragma unroll
    for (int r = 0; r < 4; ++r)
        #pragma unroll
        for (int i = 0; i < 16; ++i) acc[r][i] = 0.f;

    const int R   = bz*16 + wv*4;                  // first plane row (window R..R+5)
    const int j4b = (lane & 31) + 2*(lane >> 5);   // A-frag site base
    const char* awave = (const char*)rpt + (size_t)(R*36 + j4b)*8;

    #pragma unroll 1
    for (int p2 = 0; p2 < 3; ++p2) {
        #pragma unroll 2
        for (int j2 = 0; j2 < 6; ++j2) {
            const int it = p2*6 + j2;
            const char* aptr = awave + ((size_t)(e1+p2)*34 + (e2b+j2))*PLANE_BYTES;
            const _Float16* tb = tabm + it*1536 + lane*8;
            half8 B0 = *(const half8*)(tb);
            half8 B1 = *(const half8*)(tb + 512);
            half8 B2 = *(const half8*)(tb + 1024);
            union { ull u[2]; half8 h; } A[6];
            #pragma unroll
            for (int j3l = 0; j3l < 6; ++j3l) {
                const ull* ap = (const ull*)(aptr + j3l*288);
                A[j3l].u[0] = ap[0];
                A[j3l].u[1] = ap[1];
            }
            #pragma unroll
            for (int j3l = 0; j3l < 6; ++j3l) {
                if (j3l <= 3)
                    acc[j3l]   = __builtin_amdgcn_mfma_f32_32x32x16_f16(A[j3l].h, B0, acc[j3l],   0,0,0);
                if (j3l >= 1 && j3l <= 4)
                    acc[j3l-1] = __builtin_amdgcn_mfma_f32_32x32x16_f16(A[j3l].h, B1, acc[j3l-1], 0,0,0);
                if (j3l >= 2)
                    acc[j3l-2] = __builtin_amdgcn_mfma_f32_32x32x16_f16(A[j3l].h, B2, acc[j3l-2], 0,0,0);
            }
        }
    }

    const int n8 = lane & 7;
    const int d2 = (lane >> 3) & 3;
    const int h  = lane >> 5;
    const int sbit = n8 >> 1;
    float* outp = out + pbase + (size_t)d2*1024;
    #pragma unroll
    for (int rloc = 0; rloc < 4; ++rloc) {
        const int e3loc = wv*4 + rloc;
        float v[16];
        #pragma unroll
        for (int g = 0; g < 4; ++g) {
            unsigned mw = *(const unsigned*)&msk[d2*512 + e3loc*32 + 8*g + 4*h];
            #pragma unroll
            for (int j = 0; j < 4; ++j) {
                float a  = acc[rloc][4*g + j];
                float sg = __builtin_amdgcn_rcpf(1.f + __expf(-a));
                v[4*g+j] = ((mw >> (8*j + sbit)) & 1u) ? sg : 0.f;
            }
        }
        #pragma unroll
        for (int i = 0; i < 16; ++i) {
            v[i] += __shfl_xor(v[i], 1);
            v[i] += __shfl_xor(v[i], 2);
            v[i] += __shfl_xor(v[i], 4);
        }
        if (n8 == 0) {
            #pragma unroll
            for (int g = 0; g < 4; ++g) {
                f4 o; o.x = v[4*g]; o.y = v[4*g+1]; o.z = v[4*g+2]; o.w = v[4*g+3];
                *(f4*)(outp + e3loc*32 + 8*g + 4*h) = o;
            }
        }
    }
}

// ---------------------------------------------------------------------------
// fp32 fallback (ws too small): known-good from round 1.
// ---------------------------------------------------------------------------
__global__ void build_wtab(const float* __restrict__ w, float* __restrict__ tab) {
    int idx = blockIdx.x * blockDim.x + threadIdx.x;
    if (idx >= TAB_ELEMS) return;
    int n  = idx & 7;
    int r  = idx >> 3;
    int p5 = r % 3; r /= 3;
    int p4 = r % 3; r /= 3;
    int p3 = r % 3; r /= 3;
    int p2 = r % 3; r /= 3;
    int t  = r;
    int t1 = t >> 1, t2 = t & 1;
    int br = n & 1;
    int s  = n >> 1;
    int s1 = s >> 1, s2 = s & 1;
    int a = t1 - s1 + 1;
    int b = t2 - s2 + 1;
    int widx = (br == 0)
        ? (a*243 + b*81 + p2*27 + p3*9 + p4*3 + p5)
        : (b*243 + a*81 + p4*27 + p5*9 + p2*3 + p3);
    tab[idx] = w[widx];
}

__global__ __launch_bounds__(256)
void conv_fp32(const float* __restrict__ x,
               const float* __restrict__ tab,
               float* __restrict__ out) {
    const int e4 = threadIdx.x;
    const int e3 = blockIdx.x * 8 + threadIdx.y;
    const int e2 = blockIdx.y;
    const int e1 = blockIdx.z;

    float acc[8];
    #pragma unroll
    for (int n = 0; n < 8; ++n) acc[n] = 0.f;

    #pragma unroll 1
    for (int t = 0; t < 4; ++t) {
        const float* st  = x + (size_t)t * X_SLAB;
        const float* wt0 = tab + t * 648;
        #pragma unroll
        for (int p2 = 0; p2 < 3; ++p2) {
            #pragma unroll
            for (int p3 = 0; p3 < 3; ++p3) {
                int i1 = e1 + p2 - 1, i2 = e2 + p3 - 1;
                bool v12 = ((unsigned)i1 < 32u) && ((unsigned)i2 < 32u);
                const float* base = st + (i1*32768 + i2*1024 + (e3-1)*32 + (e4-1));
                const float* wt = wt0 + (p2*3 + p3) * 72;
                #pragma unroll
                for (int p4 = 0; p4 < 3; ++p4) {
                    int i3 = e3 + p4 - 1;
                    bool v3 = v12 && ((unsigned)i3 < 32u);
                    #pragma unroll
                    for (int p5 = 0; p5 < 3; ++p5) {
                        int i4 = e4 + p5 - 1;
                        bool ok = v3 && ((unsigned)i4 < 32u);
                        float v = ok ? fmaxf(base[p4*32 + p5], 0.f) : 0.f;
                        const float* w8 = wt + (p4*3 + p5)*8;
                        #pragma unroll
                        for (int n = 0; n < 8; ++n)
                            acc[n] = fmaf(w8[n], v, acc[n]);
                    }
                }
            }
        }
    }

    const size_t eflat = (size_t)e1*32768 + e2*1024 + e3*32 + e4;
    float res = 0.f;
    #pragma unroll
    for (int i = 0; i < 4; ++i) {
        float xv = x[(size_t)i * X_SLAB + eflat];
        float s0 = __builtin_amdgcn_rcpf(1.f + __expf(-acc[2*i]));
        float s1 = __builtin_amdgcn_rcpf(1.f + __expf(-acc[2*i+1]));
        float m  = (xv != 0.f) ? 1.f : 0.f;
        res = fmaf(m, s0 + s1, res);
    }
    out[eflat] = res;
}

// ---------------------------------------------------------------------------
extern "C" void kernel_launch(void* const* d_in, const int* in_sizes, int n_in,
                              void* d_out, int out_size, void* d_ws, size_t ws_size,
                              hipStream_t stream) {
    const float* x = (const float*)d_in[0];    // (1,2,2,32,32,32,32) fp32
    const float* w = (const float*)d_in[1];    // (729,) fp32
    float* out = (float*)d_out;                // (1,32,32,32,32) fp32

    const size_t need = (size_t)RPT_OFF + (size_t)RPT_SITES*8ull + RPT_SLACK;

    if (ws_size >= need) {
        _Float16* tabm = (_Float16*)d_ws;                     // 55296 B
        ull*      rpt  = (ull*)((char*)d_ws + RPT_OFF);
        prep<<<dim3((RPT_SITES + 255)/256), dim3(256), 0, stream>>>(x, w, rpt, tabm);
        dim3 grd(8, 32, 2), blk(256, 1, 1);
        // 5 identical, idempotent launches: marginal cost of 4 extra = 4x conv.
        conv_mfma<<<grd, blk, 0, stream>>>(x, rpt, tabm, out);
        conv_mfma<<<grd, blk, 0, stream>>>(x, rpt, tabm, out);
        conv_mfma<<<grd, blk, 0, stream>>>(x, rpt, tabm, out);
        conv_mfma<<<grd, blk, 0, stream>>>(x, rpt, tabm, out);
        conv_mfma<<<grd, blk, 0, stream>>>(x, rpt, tabm, out);
    } else {
        float* tab = (float*)d_ws;
        build_wtab<<<dim3((TAB_ELEMS + 255)/256), dim3(256), 0, stream>>>(w, tab);
        dim3 blk(32, 8, 1), grd(4, 32, 32);
        conv_fp32<<<grd, blk, 0, stream>>>(x, tab, out);
    }
}

// Round 9
// 97.693 us; speedup vs baseline: 2.0518x; 2.0518x over previous
//
#include <hip/hip_runtime.h>

typedef _Float16 half8 __attribute__((ext_vector_type(8)));
typedef float f16v __attribute__((ext_vector_type(16)));
typedef float f4 __attribute__((ext_vector_type(4)));
typedef unsigned long long ull;

#define X_SLAB   1048576            // 32^4
#define PLANE_BYTES (34*36*4*2)     // 9792: one (j1,j2) plane [j3<34][j4<36][t<4] f16
#define RPT_SITES (34*34*34*36)     // 1,414,944 sites (8B each)
#define RPT_OFF  65536              // byte offset of rp_t in ws (tab before it)
#define RPT_SLACK 4096              // covers stage-window overrun past last plane
#define TAB_N    (3*6*3*512)        // 27648 f16 entries
#define TAB_ELEMS  (4*81*8)         // fp32 fallback table

// ---------------------------------------------------------------------------
// prep: identical math to R7.
// ---------------------------------------------------------------------------
__global__ __launch_bounds__(256)
void prep(const float* __restrict__ x, const float* __restrict__ w,
          ull* __restrict__ rpt, _Float16* __restrict__ tabm) {
    unsigned s = blockIdx.x * 256 + threadIdx.x;
    if (s < RPT_SITES) {
        unsigned q = s;
        int j4 = q % 36; q /= 36;
        int j3 = q % 34; q /= 34;
        int j2 = q % 34; q /= 34;
        int j1 = q;
        union { _Float16 h[4]; ull u; } pk;
        pk.u = 0ull;
        if (j1 >= 1 && j1 <= 32 && j2 >= 1 && j2 <= 32 &&
            j3 >= 1 && j3 <= 32 && j4 >= 1 && j4 <= 32) {
            size_t off = (size_t)(j1-1)*32768 + (j2-1)*1024 + (j3-1)*32 + (j4-1);
            #pragma unroll
            for (int t = 0; t < 4; ++t)
                pk.h[t] = (_Float16)fmaxf(x[(size_t)t*X_SLAB + off], 0.f);
        }
        rpt[s] = pk.u;
    }
    if (blockIdx.x == 0) {
        for (int idx = threadIdx.x; idx < TAB_N; idx += 256) {
            int j = idx & 7, l = (idx >> 3) & 63, slice = idx >> 9;   // slice<54
            int p4 = slice % 3, j2rel = (slice/3) % 6, p2 = slice/18;
            int n32 = l & 31;
            int d2 = n32 >> 3, n8 = n32 & 7;
            int k = 8*(l>>5) + j;
            int p5h = k >> 2, t = k & 3;
            int p3 = j2rel - d2;
            float val = 0.f;
            if (p5h < 3 && p3 >= 0 && p3 <= 2) {
                int br = n8 & 1, sc = n8 >> 1, s1 = sc >> 1, s2 = sc & 1;
                int t1 = t >> 1, t2 = t & 1;
                int a = t1 - s1 + 1, b = t2 - s2 + 1;
                int widx = (br == 0)
                    ? (a*243 + b*81 + p2*27 + p3*9 + p4*3 + p5h)
                    : (b*243 + a*81 + p4*27 + p5h*9 + p2*3 + p3);
                val = w[widx];
            }
            tabm[idx] = (_Float16)val;
        }
    }
}

// ---------------------------------------------------------------------------
// conv_mfma: per-wave barrier-free async pipeline (AITER-style fine vmcnt).
// Each wave owns 4 e3-rows; per (p2,j2) plane-iter it DMAs its 2KB row-window
// into a private LDS slot (2x global_load_lds 16B), double-buffered one iter
// ahead; s_waitcnt vmcnt(5) keeps the next stage + next B in flight. No
// __syncthreads in the K-loop.
// Queue invariant entering iter: [stage(it)x2, B(it)x3]; after issuing next:
// [s(it)2, B(it)3, s(nit)2, B(nit)3] -> vmcnt(5) drains exactly s(it)+B(it).
// ---------------------------------------------------------------------------
__global__ __launch_bounds__(256)
void conv_mfma(const float* __restrict__ x, const ull* __restrict__ rpt,
               const _Float16* __restrict__ tabm, float* __restrict__ out) {
    __shared__ __align__(16) unsigned char stg[4][2][2048];   // per-wave dbuf
    __shared__ unsigned char msk[2048];

    const int tid  = threadIdx.x;
    const int lane = tid & 63;
    const int wv   = tid >> 6;                     // 0..3
    const int e2b  = blockIdx.x * 4;
    const int e1   = blockIdx.y;
    const int bz   = blockIdx.z;                   // e3 half
    const size_t pbase = (size_t)e1*32768 + (size_t)e2b*1024 + (size_t)bz*512;

    // mask nibbles for the block's 2048 points: msk[d2*512 + e3loc*32 + e4]
    {
        int p0 = tid * 8;
        int d2 = p0 >> 9, rem = p0 & 511;
        const float* xb = x + pbase + (size_t)d2*1024 + rem;
        #pragma unroll
        for (int g = 0; g < 2; ++g) {
            f4 a0 = *(const f4*)(xb + (size_t)0*X_SLAB + 4*g);
            f4 a1 = *(const f4*)(xb + (size_t)1*X_SLAB + 4*g);
            f4 a2 = *(const f4*)(xb + (size_t)2*X_SLAB + 4*g);
            f4 a3 = *(const f4*)(xb + (size_t)3*X_SLAB + 4*g);
            unsigned wbits = 0;
            #pragma unroll
            for (int q = 0; q < 4; ++q) {
                unsigned b = (a0[q] != 0.f ? 1u : 0u) | (a1[q] != 0.f ? 2u : 0u)
                           | (a2[q] != 0.f ? 4u : 0u) | (a3[q] != 0.f ? 8u : 0u);
                wbits |= b << (8*q);
            }
            *(unsigned*)&msk[p0 + 4*g] = wbits;
        }
    }
    __syncthreads();                  // the only block-wide barrier

    f16v acc[4];
    #pragma unroll
    for (int r = 0; r < 4; ++r)
        #pragma unroll
        for (int i = 0; i < 16; ++i) acc[r][i] = 0.f;

    const int R     = bz*16 + wv*4;                    // row window R..R+5
    const int j4off = (lane & 31)*8 + (lane >> 5)*16;  // A-frag byte offset in row
    // global source base for this wave's stage window (lane*16 DMA pattern)
    const char* aglob0 = (const char*)rpt + (size_t)R*288 + lane*16;

    // stage plane `it` into LDS slot `slot`
    auto stage_to = [&](int it, int slot) {
        int p2 = it / 6, j2 = it - p2*6;
        const char* src = aglob0 + ((size_t)(e1+p2)*34 + (e2b+j2))*PLANE_BYTES;
        unsigned char* dst = &stg[wv][slot][0] + lane*16;
        #pragma unroll
        for (int k = 0; k < 2; ++k)
            __builtin_amdgcn_global_load_lds(
                (const __attribute__((address_space(1))) unsigned int*)(src + k*1024),
                (__attribute__((address_space(3))) unsigned int*)(dst + k*1024),
                16, 0, 0);
    };
    auto loadB = [&](int it, half8* B) {
        const _Float16* tb = tabm + it*1536 + lane*8;
        B[0] = *(const half8*)(tb);
        B[1] = *(const half8*)(tb + 512);
        B[2] = *(const half8*)(tb + 1024);
    };
    auto compute = [&](int slot, const half8* B) {
        const unsigned char* sb = &stg[wv][slot][0];
        union { ull u[2]; half8 h; } A[6];
        #pragma unroll
        for (int j3l = 0; j3l < 6; ++j3l) {
            const ull* ap = (const ull*)(sb + j3l*288 + j4off);
            A[j3l].u[0] = ap[0];
            A[j3l].u[1] = ap[1];
        }
        #pragma unroll
        for (int j3l = 0; j3l < 6; ++j3l) {
            if (j3l <= 3)
                acc[j3l]   = __builtin_amdgcn_mfma_f32_32x32x16_f16(A[j3l].h, B[0], acc[j3l],   0,0,0);
            if (j3l >= 1 && j3l <= 4)
                acc[j3l-1] = __builtin_amdgcn_mfma_f32_32x32x16_f16(A[j3l].h, B[1], acc[j3l-1], 0,0,0);
            if (j3l >= 2)
                acc[j3l-2] = __builtin_amdgcn_mfma_f32_32x32x16_f16(A[j3l].h, B[2], acc[j3l-2], 0,0,0);
        }
    };

    half8 Ba[3], Bb[3];
    stage_to(0, 0);
    loadB(0, Ba);

    #pragma unroll 1
    for (int ip = 0; ip < 9; ++ip) {
        const int itE = 2*ip;
        // even iteration: consume slot0/Ba, prefetch itE+1 into slot1/Bb
        {
            int nit = itE + 1;                    // <= 17 always
            stage_to(nit, 1);
            loadB(nit, Bb);
            asm volatile("s_waitcnt vmcnt(5)" ::: "memory");
            compute(0, Ba);
        }
        // odd iteration: consume slot1/Bb, prefetch itE+2 (dummy=17 at end)
        {
            int nit = (itE + 2 < 18) ? itE + 2 : 17;   // dummy re-stage at tail
            stage_to(nit, 0);
            loadB(nit, Ba);
            asm volatile("s_waitcnt vmcnt(5)" ::: "memory");
            compute(1, Bb);
        }
    }

    // ---- epilogue ----
    // D layout: col n32 = lane&31 (d2 = n32>>3, n8 = n32&7),
    // row m(e4) = (reg&3) + 8*(reg>>2) + 4*(lane>>5)
    const int n8 = lane & 7;
    const int d2 = (lane >> 3) & 3;
    const int h  = lane >> 5;
    const int sbit = n8 >> 1;
    float* outp = out + pbase + (size_t)d2*1024;
    #pragma unroll
    for (int rloc = 0; rloc < 4; ++rloc) {
        const int e3loc = wv*4 + rloc;
        float v[16];
        #pragma unroll
        for (int g = 0; g < 4; ++g) {
            unsigned mw = *(const unsigned*)&msk[d2*512 + e3loc*32 + 8*g + 4*h];
            #pragma unroll
            for (int j = 0; j < 4; ++j) {
                float a  = acc[rloc][4*g + j];
                float sg = __builtin_amdgcn_rcpf(1.f + __expf(-a));
                v[4*g+j] = ((mw >> (8*j + sbit)) & 1u) ? sg : 0.f;
            }
        }
        #pragma unroll
        for (int i = 0; i < 16; ++i) {
            v[i] += __shfl_xor(v[i], 1);
            v[i] += __shfl_xor(v[i], 2);
            v[i] += __shfl_xor(v[i], 4);
        }
        if (n8 == 0) {
            #pragma unroll
            for (int g = 0; g < 4; ++g) {
                f4 o; o.x = v[4*g]; o.y = v[4*g+1]; o.z = v[4*g+2]; o.w = v[4*g+3];
                *(f4*)(outp + e3loc*32 + 8*g + 4*h) = o;
            }
        }
    }
}

// ---------------------------------------------------------------------------
// fp32 fallback (ws too small): known-good from round 1.
// ---------------------------------------------------------------------------
__global__ void build_wtab(const float* __restrict__ w, float* __restrict__ tab) {
    int idx = blockIdx.x * blockDim.x + threadIdx.x;
    if (idx >= TAB_ELEMS) return;
    int n  = idx & 7;
    int r  = idx >> 3;
    int p5 = r % 3; r /= 3;
    int p4 = r % 3; r /= 3;
    int p3 = r % 3; r /= 3;
    int p2 = r % 3; r /= 3;
    int t  = r;
    int t1 = t >> 1, t2 = t & 1;
    int br = n & 1;
    int s  = n >> 1;
    int s1 = s >> 1, s2 = s & 1;
    int a = t1 - s1 + 1;
    int b = t2 - s2 + 1;
    int widx = (br == 0)
        ? (a*243 + b*81 + p2*27 + p3*9 + p4*3 + p5)
        : (b*243 + a*81 + p4*27 + p5*9 + p2*3 + p3);
    tab[idx] = w[widx];
}

__global__ __launch_bounds__(256)
void conv_fp32(const float* __restrict__ x,
               const float* __restrict__ tab,
               float* __restrict__ out) {
    const int e4 = threadIdx.x;
    const int e3 = blockIdx.x * 8 + threadIdx.y;
    const int e2 = blockIdx.y;
    const int e1 = blockIdx.z;

    float acc[8];
    #pragma unroll
    for (int n = 0; n < 8; ++n) acc[n] = 0.f;

    #pragma unroll 1
    for (int t = 0; t < 4; ++t) {
        const float* st  = x + (size_t)t * X_SLAB;
        const float* wt0 = tab + t * 648;
        #pragma unroll
        for (int p2 = 0; p2 < 3; ++p2) {
            #pragma unroll
            for (int p3 = 0; p3 < 3; ++p3) {
                int i1 = e1 + p2 - 1, i2 = e2 + p3 - 1;
                bool v12 = ((unsigned)i1 < 32u) && ((unsigned)i2 < 32u);
                const float* base = st + (i1*32768 + i2*1024 + (e3-1)*32 + (e4-1));
                const float* wt = wt0 + (p2*3 + p3) * 72;
                #pragma unroll
                for (int p4 = 0; p4 < 3; ++p4) {
                    int i3 = e3 + p4 - 1;
                    bool v3 = v12 && ((unsigned)i3 < 32u);
                    #pragma unroll
                    for (int p5 = 0; p5 < 3; ++p5) {
                        int i4 = e4 + p5 - 1;
                        bool ok = v3 && ((unsigned)i4 < 32u);
                        float v = ok ? fmaxf(base[p4*32 + p5], 0.f) : 0.f;
                        const float* w8 = wt + (p4*3 + p5)*8;
                        #pragma unroll
                        for (int n = 0; n < 8; ++n)
                            acc[n] = fmaf(w8[n], v, acc[n]);
                    }
                }
            }
        }
    }

    const size_t eflat = (size_t)e1*32768 + e2*1024 + e3*32 + e4;
    float res = 0.f;
    #pragma unroll
    for (int i = 0; i < 4; ++i) {
        float xv = x[(size_t)i * X_SLAB + eflat];
        float s0 = __builtin_amdgcn_rcpf(1.f + __expf(-acc[2*i]));
        float s1 = __builtin_amdgcn_rcpf(1.f + __expf(-acc[2*i+1]));
        float m  = (xv != 0.f) ? 1.f : 0.f;
        res = fmaf(m, s0 + s1, res);
    }
    out[eflat] = res;
}

// ---------------------------------------------------------------------------
extern "C" void kernel_launch(void* const* d_in, const int* in_sizes, int n_in,
                              void* d_out, int out_size, void* d_ws, size_t ws_size,
                              hipStream_t stream) {
    const float* x = (const float*)d_in[0];    // (1,2,2,32,32,32,32) fp32
    const float* w = (const float*)d_in[1];    // (729,) fp32
    float* out = (float*)d_out;                // (1,32,32,32,32) fp32

    const size_t need = (size_t)RPT_OFF + (size_t)RPT_SITES*8ull + RPT_SLACK;

    if (ws_size >= need) {
        _Float16* tabm = (_Float16*)d_ws;                     // 55296 B
        ull*      rpt  = (ull*)((char*)d_ws + RPT_OFF);
        prep<<<dim3((RPT_SITES + 255)/256), dim3(256), 0, stream>>>(x, w, rpt, tabm);
        dim3 grd(8, 32, 2), blk(256, 1, 1);
        conv_mfma<<<grd, blk, 0, stream>>>(x, rpt, tabm, out);
    } else {
        float* tab = (float*)d_ws;
        build_wtab<<<dim3((TAB_ELEMS + 255)/256), dim3(256), 0, stream>>>(w, tab);
        dim3 blk(32, 8, 1), grd(4, 32, 32);
        conv_fp32<<<grd, blk, 0, stream>>>(x, tab, out);
    }
}